// Round 3
// baseline (383.123 us; speedup 1.0000x reference)
//
#include <hip/hip_runtime.h>
#include <hip/hip_bf16.h>

typedef short    short8  __attribute__((ext_vector_type(8)));
typedef unsigned uint2v  __attribute__((ext_vector_type(2)));
typedef float    f32x4   __attribute__((ext_vector_type(4)));

#define B_TOT 4096
#define SEQ   256
#define NDOF  7
#define HDIM  256
#define ROWS  16
#define DTF   0.002f

// RNE float->bf16 (setup only)
static __device__ __forceinline__ unsigned short f2bf(float f) {
    union { float f; unsigned u; } u; u.f = f;
    unsigned x = u.u;
    unsigned r = (x + 0x7FFFu + ((x >> 16) & 1u)) >> 16;
    return (unsigned short)r;
}
static __device__ __forceinline__ unsigned cvt_pk_bf16(float lo, float hi) {
    unsigned r;
    asm("v_cvt_pk_bf16_f32 %0, %1, %2" : "=v"(r) : "v"(lo), "v"(hi));
    return r;
}
static __device__ __forceinline__ float silu(float p) {
    return p * __builtin_amdgcn_rcpf(1.0f + __expf(-p));
}

__global__ __launch_bounds__(512, 2)
void NeuralODE_kernel(const float* __restrict__ st0, const float* __restrict__ tq,
                      const float* __restrict__ W1,  const float* __restrict__ b1,
                      const float* __restrict__ W2,  const float* __restrict__ b2,
                      const float* __restrict__ W3,  const float* __restrict__ b3,
                      float* __restrict__ out)
{
    __shared__ __align__(16) short h1b[16 * 264];
    __shared__ __align__(16) short h2b[16 * 264];
    __shared__ __align__(16) float red[4][16][12];
    __shared__ __align__(16) float b2l[HDIM];

    const int tid  = threadIdx.x;
    const int w    = tid >> 6;          // 8 waves
    const int lane = tid & 63;
    const int g    = lane >> 4;
    const int n    = lane & 15;
    const int b0   = blockIdx.x * ROWS;
    const int mb   = 32 * w;

    if (tid < HDIM) b2l[tid] = b2[tid];

    // ---------------- weight fragments (transposed GEMM; bias b1 folded at k==7) --
    short8 a1f[2];
#pragma unroll
    for (int t = 0; t < 2; ++t) {
        short8 fr;
#pragma unroll
        for (int j = 0; j < 8; ++j) {
            int k = 8 * g + j;   // x: 0-6=q, 7=1(bias), 8-14=v, 15=0, 16-22=tau, 23+=0
            int m = mb + 16 * t + n;
            float v;
            if (k < 7)        v = W1[k * HDIM + m];
            else if (k == 7)  v = b1[m];
            else if (k < 15)  v = W1[(k - 1) * HDIM + m];
            else if (k == 15) v = 0.0f;
            else if (k < 23)  v = W1[(k - 2) * HDIM + m];
            else              v = 0.0f;
            fr[j] = (short)f2bf(v);
        }
        a1f[t] = fr;
    }
    short8 a2f[2][8];
#pragma unroll
    for (int t = 0; t < 2; ++t)
#pragma unroll
        for (int ks = 0; ks < 8; ++ks) {
            short8 fr;
#pragma unroll
            for (int j = 0; j < 8; ++j) {
                int k = 32 * ks + 8 * g + j;
                fr[j] = (short)f2bf(W2[(size_t)k * HDIM + mb + 16 * t + n]);
            }
            a2f[t][ks] = fr;
        }
    short8 a3f[2] = {};
    if (w < 4) {
#pragma unroll
        for (int s = 0; s < 2; ++s) {
            short8 fr;
#pragma unroll
            for (int j = 0; j < 8; ++j) {
                int k = 64 * w + 32 * s + 8 * g + j;
                fr[j] = (n < NDOF) ? (short)f2bf(W3[k * NDOF + n]) : (short)0;
            }
            a3f[s] = fr;
        }
    }
    f32x4 b3v;
#pragma unroll
    for (int r = 0; r < 4; ++r) {
        int m = 4 * g + r;
        b3v[r] = (m < NDOF) ? b3[m] : 0.0f;
    }

    // ---------------- per-lane replicated state: full q, v, a in registers -------
    float q[7], v[7], aold[8], tn[8];
    const float* sp = st0 + (size_t)(b0 + n) * 14;
#pragma unroll
    for (int d = 0; d < 7; ++d) { q[d] = sp[d]; v[d] = sp[7 + d]; aold[d] = 0.0f; }
    aold[7] = 0.0f;
#pragma unroll
    for (int d = 0; d < 8; ++d) tn[d] = 0.0f;   // g!=2 lanes keep zeros (NaN safety)

    const float* tqb = tq + (size_t)(b0 + n) * (SEQ * NDOF);

    auto pf_tau = [&](int idx) {
        if (g == 2) {
            const float* tp = tqb + (size_t)idx * NDOF;
#pragma unroll
            for (int d = 0; d < 7; ++d) tn[d] = tp[d];
        }
    };

    // lane builds its own xf fragment: g0=q+bias, g1=v_pred, g2=tau, g3=0
    auto build_xf = [&](const float qq[7], const float vv7[7]) -> short8 {
        union { unsigned u[4]; short8 s; } xu;
#pragma unroll
        for (int r = 0; r < 4; ++r) {
            float lo = (g == 0) ? qq[2 * r] : vv7[2 * r];
            float hi = (r == 3) ? ((g == 0) ? 1.0f : 0.0f)
                                : ((g == 0) ? qq[2 * r + 1] : vv7[2 * r + 1]);
            unsigned pw = cvt_pk_bf16(lo, hi);
            unsigned tw = cvt_pk_bf16(tn[2 * r], (r == 3) ? 0.0f : tn[2 * r + 1]);
            xu.u[r] = (g < 2) ? pw : tw;
        }
        return xu.s;
    };

    auto accel = [&](short8 xf, f32x4& alo, f32x4& ahi) {
        const f32x4 cz = {0.0f, 0.0f, 0.0f, 0.0f};
        // bias for L2 from LDS (broadcast read, issued early)
        f32x4 c2a = *(const f32x4*)&b2l[mb + 4 * g];
        f32x4 c2b = *(const f32x4*)&b2l[mb + 16 + 4 * g];

        // L1
        f32x4 c1a = __builtin_amdgcn_mfma_f32_16x16x32_bf16(a1f[0], xf, cz, 0, 0, 0);
        f32x4 c1b = __builtin_amdgcn_mfma_f32_16x16x32_bf16(a1f[1], xf, cz, 0, 0, 0);
        {
            uint2v p;
            p[0] = cvt_pk_bf16(silu(c1a[0]), silu(c1a[1]));
            p[1] = cvt_pk_bf16(silu(c1a[2]), silu(c1a[3]));
            *(uint2v*)&h1b[n * 264 + mb + 4 * g] = p;
            p[0] = cvt_pk_bf16(silu(c1b[0]), silu(c1b[1]));
            p[1] = cvt_pk_bf16(silu(c1b[2]), silu(c1b[3]));
            *(uint2v*)&h1b[n * 264 + mb + 16 + 4 * g] = p;
        }
        __syncthreads();   // B1

        // L2
#pragma unroll
        for (int ks = 0; ks < 8; ++ks) {
            short8 bfr = *(const short8*)&h1b[n * 264 + 32 * ks + 8 * g];
            c2a = __builtin_amdgcn_mfma_f32_16x16x32_bf16(a2f[0][ks], bfr, c2a, 0, 0, 0);
            c2b = __builtin_amdgcn_mfma_f32_16x16x32_bf16(a2f[1][ks], bfr, c2b, 0, 0, 0);
        }
        {
            uint2v p;
            p[0] = cvt_pk_bf16(silu(c2a[0]), silu(c2a[1]));
            p[1] = cvt_pk_bf16(silu(c2a[2]), silu(c2a[3]));
            *(uint2v*)&h2b[n * 264 + mb + 4 * g] = p;
            p[0] = cvt_pk_bf16(silu(c2b[0]), silu(c2b[1]));
            p[1] = cvt_pk_bf16(silu(c2b[2]), silu(c2b[3]));
            *(uint2v*)&h2b[n * 264 + mb + 16 + 4 * g] = p;
        }
        __syncthreads();   // B2

        // L3: waves 0..3 compute K-chunk partials (b3 folded into wave 0's init)
        if (w < 4) {
            short8 p0 = *(const short8*)&h2b[n * 264 + 64 * w + 8 * g];
            short8 p1 = *(const short8*)&h2b[n * 264 + 64 * w + 32 + 8 * g];
            f32x4 ci = (w == 0) ? b3v : cz;
            f32x4 c3 = __builtin_amdgcn_mfma_f32_16x16x32_bf16(a3f[0], p0, ci, 0, 0, 0);
            c3 = __builtin_amdgcn_mfma_f32_16x16x32_bf16(a3f[1], p1, c3, 0, 0, 0);
            if (g < 2) *(f32x4*)&red[w][n][4 * g] = c3;
        }
        __syncthreads();   // B3

        // everyone: reduce 4 partials, then xor-16 swizzle -> full a in every lane
        const float* rp = &red[0][0][0];
        const int ro = n * 12 + 4 * (g & 1);
        f32x4 s0 = *(const f32x4*)(rp + ro)       + *(const f32x4*)(rp + 192 + ro);
        f32x4 s1 = *(const f32x4*)(rp + 384 + ro) + *(const f32x4*)(rp + 576 + ro);
        f32x4 cc = s0 + s1;
#pragma unroll
        for (int r = 0; r < 4; ++r) {
            float sw = __int_as_float(
                __builtin_amdgcn_ds_swizzle(__float_as_int(cc[r]), 0x401F)); // lane^16
            bool odd = (g & 1) != 0;
            alo[r] = odd ? sw    : cc[r];
            ahi[r] = odd ? cc[r] : sw;
        }
    };

    __syncthreads();   // b2l visible

    // ---------------- prologue: a0 = accel(x0), tau idx 0 -------------------------
    pf_tau(0);
    {
        short8 xf0 = build_xf(q, v);
        { float tt = 1.0f * DTF; int ns = (int)floorf(tt / DTF);
          if (ns > SEQ - 1) ns = SEQ - 1; pf_tau(ns); }
        f32x4 alo, ahi;
        accel(xf0, alo, ahi);
#pragma unroll
        for (int d = 0; d < 7; ++d) aold[d] = (d < 4) ? alo[d] : ahi[d - 4];
    }

    // ---------------- 256 Verlet steps --------------------------------------------
    float* op = out + (size_t)(b0 + n) * SEQ * 14;

#pragma unroll 1
    for (int i = 0; i < SEQ; ++i) {
        float vp[7];
#pragma unroll
        for (int d = 0; d < 7; ++d) {
            q[d]  = q[d] + v[d] * DTF + aold[d] * (0.5f * DTF * DTF);
            vp[d] = v[d] + aold[d] * DTF;
        }

        short8 xf = build_xf(q, vp);

        // prefetch tau for next step (same index formula as the passing R2 kernel)
        {
            float tt = (float)(i + 2) * DTF;
            int ns = (int)floorf(tt / DTF);
            if (ns > SEQ - 1) ns = SEQ - 1;
            pf_tau(ns);
        }

        f32x4 alo, ahi;
        accel(xf, alo, ahi);

#pragma unroll
        for (int d = 0; d < 7; ++d) {
            float an = (d < 4) ? alo[d] : ahi[d - 4];
            v[d]    = v[d] + (aold[d] + an) * (0.5f * DTF);
            aold[d] = an;
        }

        if (w == 0 && g == 0) {
            float* o = op + (size_t)i * 14;
#pragma unroll
            for (int d = 0; d < 7; ++d) { o[d] = q[d]; o[7 + d] = v[d]; }
        }
    }
}

extern "C" void kernel_launch(void* const* d_in, const int* in_sizes, int n_in,
                              void* d_out, int out_size, void* d_ws, size_t ws_size,
                              hipStream_t stream) {
    (void)in_sizes; (void)n_in; (void)d_ws; (void)ws_size; (void)out_size;
    const float* st0 = (const float*)d_in[0];
    const float* tq  = (const float*)d_in[1];
    const float* W1  = (const float*)d_in[2];
    const float* b1  = (const float*)d_in[3];
    const float* W2  = (const float*)d_in[4];
    const float* b2  = (const float*)d_in[5];
    const float* W3  = (const float*)d_in[6];
    const float* b3  = (const float*)d_in[7];

    NeuralODE_kernel<<<dim3(B_TOT / ROWS), dim3(512), 0, stream>>>(
        st0, tq, W1, b1, W2, b2, W3, b3, (float*)d_out);
}